// Round 1
// baseline (187.841 us; speedup 1.0000x reference)
//
#include <hip/hip_runtime.h>
#include <climits>

// BoundingBox: mask [128,1,512,512] fp32 -> bbox [128,4] int32 (ymin,xmin,ymax+1,xmax+1)
// THRESH = 0.5; if no pixel >= THRESH anywhere, result is (0,0,H,W).

#define THRESH 0.5f

static constexpr int N = 128;
static constexpr int H = 512;
static constexpr int W = 512;
static constexpr int G = 8;          // row-groups per image -> 128*8 = 1024 blocks
static constexpr int ROWS = H / G;   // 64 rows per block
static constexpr int BLK = 256;      // threads per block (4 waves)
static constexpr int W4 = W / 4;     // float4 per row = 128

__global__ __launch_bounds__(BLK)
void bbox_partial(const float* __restrict__ mask, int* __restrict__ partials) {
    const int n = blockIdx.x;   // image
    const int g = blockIdx.y;   // row group
    const float4* base =
        (const float4*)(mask + (size_t)n * H * W + (size_t)g * ROWS * W);

    int ymin = INT_MAX, ymax = -1, xmin = INT_MAX, xmax = -1;

    // ROWS * W4 = 64 * 128 = 8192 float4 per block; 32 per thread, coalesced.
    #pragma unroll 4
    for (int i = threadIdx.x; i < ROWS * W4; i += BLK) {
        float4 v = base[i];
        int h = g * ROWS + (i >> 7);      // i / W4
        int w = (i & (W4 - 1)) << 2;      // (i % W4) * 4
        bool b0 = v.x >= THRESH;
        bool b1 = v.y >= THRESH;
        bool b2 = v.z >= THRESH;
        bool b3 = v.w >= THRESH;
        if (b0 | b1 | b2 | b3) { ymin = min(ymin, h); ymax = max(ymax, h); }
        if (b0) { xmin = min(xmin, w + 0); xmax = max(xmax, w + 0); }
        if (b1) { xmin = min(xmin, w + 1); xmax = max(xmax, w + 1); }
        if (b2) { xmin = min(xmin, w + 2); xmax = max(xmax, w + 2); }
        if (b3) { xmin = min(xmin, w + 3); xmax = max(xmax, w + 3); }
    }

    // Wave (64-lane) shuffle reduction.
    #pragma unroll
    for (int off = 32; off > 0; off >>= 1) {
        ymin = min(ymin, __shfl_down(ymin, off, 64));
        ymax = max(ymax, __shfl_down(ymax, off, 64));
        xmin = min(xmin, __shfl_down(xmin, off, 64));
        xmax = max(xmax, __shfl_down(xmax, off, 64));
    }

    __shared__ int s[BLK / 64][4];
    const int wave = threadIdx.x >> 6;
    const int lane = threadIdx.x & 63;
    if (lane == 0) {
        s[wave][0] = ymin; s[wave][1] = ymax; s[wave][2] = xmin; s[wave][3] = xmax;
    }
    __syncthreads();
    if (threadIdx.x == 0) {
        int a = s[0][0], b = s[0][1], c = s[0][2], d = s[0][3];
        #pragma unroll
        for (int wv = 1; wv < BLK / 64; ++wv) {
            a = min(a, s[wv][0]); b = max(b, s[wv][1]);
            c = min(c, s[wv][2]); d = max(d, s[wv][3]);
        }
        int* p = partials + ((n * G + g) << 2);
        p[0] = a; p[1] = b; p[2] = c; p[3] = d;
    }
}

__global__ __launch_bounds__(128)
void bbox_final(const int* __restrict__ partials, int* __restrict__ out) {
    const int n = threadIdx.x;   // one block of 128 threads, one image each
    if (n >= N) return;
    int ymin = INT_MAX, ymax = -1, xmin = INT_MAX, xmax = -1;
    #pragma unroll
    for (int g = 0; g < G; ++g) {
        const int* p = partials + ((n * G + g) << 2);
        ymin = min(ymin, p[0]); ymax = max(ymax, p[1]);
        xmin = min(xmin, p[2]); xmax = max(xmax, p[3]);
    }
    int4 r;
    if (ymax < 0) {
        r = make_int4(0, 0, H, W);           // no hit anywhere
    } else {
        r = make_int4(ymin, xmin, ymax + 1, xmax + 1);
    }
    ((int4*)out)[n] = r;
}

extern "C" void kernel_launch(void* const* d_in, const int* in_sizes, int n_in,
                              void* d_out, int out_size, void* d_ws, size_t ws_size,
                              hipStream_t stream) {
    const float* mask = (const float*)d_in[0];
    int* partials = (int*)d_ws;              // N*G*4 ints = 16 KB, no init needed
    int* out = (int*)d_out;

    dim3 grid(N, G);
    bbox_partial<<<grid, BLK, 0, stream>>>(mask, partials);
    bbox_final<<<1, 128, 0, stream>>>(partials, out);
}